// Round 1
// baseline (235.992 us; speedup 1.0000x reference)
//
#include <hip/hip_runtime.h>
#include <math.h>

// Cached SDPA decode: B=8 H=32 Q=1 D=128, MAX_SEQ=4096, fp32 in/out.
// Flash-decode split-K: kernel1 computes per-(bh,split) online-softmax
// partials (o[128], m, l) into d_ws; kernel2 combines 8 splits per head.

#define BH_     256            // B*H
#define D_      128
#define MAXS_   4096
#define NSPLIT_ 8
#define CHUNK_  (MAXS_ / NSPLIT_)   // 512 keys per block
#define NWAVES_ 4
#define KPW_    (CHUNK_ / NWAVES_)  // 128 keys per wave
#define PSTRIDE_ (D_ + 2)           // o[128], m, l

__global__ __launch_bounds__(256) void attn_partial_kernel(
    const float* __restrict__ q,
    const float* __restrict__ knew,
    const float* __restrict__ vnew,
    const float* __restrict__ ck,
    const float* __restrict__ cv,
    const int*   __restrict__ cpos_p,
    float*       __restrict__ part)
{
    const int bh    = blockIdx.x;        // 0..255
    const int split = blockIdx.y;        // 0..7
    const int wave  = threadIdx.x >> 6;  // 0..3
    const int lane  = threadIdx.x & 63;

    const int cpos    = cpos_p[0];
    const int end_pos = cpos + 1;        // new_seq_len == 1

    const float scale = 0.08838834764831845f;  // 1/sqrt(128)

    // lane i owns dims 2i, 2i+1  -> 8 B/lane, 512 B/wave = one full row
    const float2 qv = *(const float2*)(q + (size_t)bh * D_ + lane * 2);

    const int base  = split * CHUNK_ + wave * KPW_;
    int limit = end_pos - base;
    limit = limit < 0 ? 0 : (limit > KPW_ ? KPW_ : limit);

    float m = -INFINITY;
    float l = 0.0f;
    float ox = 0.0f, oy = 0.0f;

    const float* __restrict__ ckb = ck + (size_t)bh * MAXS_ * D_;
    const float* __restrict__ cvb = cv + (size_t)bh * MAXS_ * D_;
    const float* __restrict__ knb = knew + (size_t)bh * D_;
    const float* __restrict__ vnb = vnew + (size_t)bh * D_;

    #pragma unroll 4
    for (int i = 0; i < limit; ++i) {
        const int s = base + i;
        // logical cache update: row cpos comes from the new key/value
        const float* krow = (s == cpos) ? knb : (ckb + (size_t)s * D_);
        const float* vrow = (s == cpos) ? vnb : (cvb + (size_t)s * D_);
        const float2 kv = *(const float2*)(krow + lane * 2);
        const float2 vv = *(const float2*)(vrow + lane * 2);

        float dp = qv.x * kv.x + qv.y * kv.y;
        #pragma unroll
        for (int off = 32; off > 0; off >>= 1)
            dp += __shfl_xor(dp, off);

        const float sc   = dp * scale;
        const float mn   = fmaxf(m, sc);
        const float corr = __expf(m - mn);   // first iter: exp(-inf)=0
        const float p    = __expf(sc - mn);
        l  = l  * corr + p;
        ox = ox * corr + p * vv.x;
        oy = oy * corr + p * vv.y;
        m  = mn;
    }

    // combine the 4 wave-partials via LDS -> one partial per block
    __shared__ float s_o[NWAVES_][D_];
    __shared__ float s_m[NWAVES_];
    __shared__ float s_l[NWAVES_];
    s_o[wave][lane * 2]     = ox;
    s_o[wave][lane * 2 + 1] = oy;
    if (lane == 0) { s_m[wave] = m; s_l[wave] = l; }
    __syncthreads();

    if (wave == 0) {
        const float m0 = s_m[0], m1 = s_m[1], m2 = s_m[2], m3 = s_m[3];
        const float M  = fmaxf(fmaxf(m0, m1), fmaxf(m2, m3));
        float* pp = part + ((size_t)bh * NSPLIT_ + split) * PSTRIDE_;
        if (M == -INFINITY) {
            // whole block past end_pos (can't happen for cpos=4095; stay safe)
            pp[lane * 2]     = 0.0f;
            pp[lane * 2 + 1] = 0.0f;
            if (lane == 0) { pp[D_] = -INFINITY; pp[D_ + 1] = 0.0f; }
        } else {
            const float w0 = __expf(m0 - M), w1 = __expf(m1 - M);
            const float w2 = __expf(m2 - M), w3 = __expf(m3 - M);
            const float L = w0 * s_l[0] + w1 * s_l[1] + w2 * s_l[2] + w3 * s_l[3];
            const int d0 = lane * 2, d1 = d0 + 1;
            const float a0 = w0 * s_o[0][d0] + w1 * s_o[1][d0]
                           + w2 * s_o[2][d0] + w3 * s_o[3][d0];
            const float a1 = w0 * s_o[0][d1] + w1 * s_o[1][d1]
                           + w2 * s_o[2][d1] + w3 * s_o[3][d1];
            pp[d0] = a0;
            pp[d1] = a1;
            if (lane == 0) { pp[D_] = M; pp[D_ + 1] = L; }
        }
    }
}

__global__ __launch_bounds__(128) void attn_combine_kernel(
    const float* __restrict__ part,
    float*       __restrict__ out)
{
    const int bh = blockIdx.x;   // 0..255
    const int d  = threadIdx.x;  // 0..127
    const float* pb = part + (size_t)bh * NSPLIT_ * PSTRIDE_;

    float M = -INFINITY;
    #pragma unroll
    for (int p = 0; p < NSPLIT_; ++p)
        M = fmaxf(M, pb[p * PSTRIDE_ + D_]);

    float L = 0.0f, acc = 0.0f;
    #pragma unroll
    for (int p = 0; p < NSPLIT_; ++p) {
        const float mp = pb[p * PSTRIDE_ + D_];
        const float w  = (mp == -INFINITY) ? 0.0f : __expf(mp - M);
        L   += w * pb[p * PSTRIDE_ + D_ + 1];
        acc += w * pb[p * PSTRIDE_ + d];
    }
    out[(size_t)bh * D_ + d] = acc / L;
}

extern "C" void kernel_launch(void* const* d_in, const int* in_sizes, int n_in,
                              void* d_out, int out_size, void* d_ws, size_t ws_size,
                              hipStream_t stream) {
    const float* q    = (const float*)d_in[0];
    const float* knew = (const float*)d_in[1];
    const float* vnew = (const float*)d_in[2];
    const float* ck   = (const float*)d_in[3];
    const float* cv   = (const float*)d_in[4];
    const int*   cpos = (const int*)d_in[5];
    float* out  = (float*)d_out;
    float* part = (float*)d_ws;   // needs 256*8*130*4 = 1,064,960 B

    dim3 grid1(BH_, NSPLIT_);
    attn_partial_kernel<<<grid1, 256, 0, stream>>>(q, knew, vnew, ck, cv, cpos, part);
    attn_combine_kernel<<<BH_, 128, 0, stream>>>(part, out);
}

// Round 2
// 192.858 us; speedup vs baseline: 1.2237x; 1.2237x over previous
//
#include <hip/hip_runtime.h>
#include <math.h>

// Cached SDPA decode: B=8 H=32 Q=1 D=128, MAX_SEQ=4096, fp32 in/out.
// Flash-decode split-K. Kernel1: per-(bh,split) online-softmax partials over
// cache rows [0, cpos) only -- the new key/value is merged as an extra
// partial inside kernel2. Two keys per wave-iteration (lanes 0-31 = key s0,
// lanes 32-63 = key s0+1), float4/lane = 16B/lane fully-coalesced 1KB/wave.

#define BH_     256                  // B*H
#define D_      128
#define MAXS_   4096
#define NSPLIT_ 8
#define CHUNK_  (MAXS_ / NSPLIT_)    // 512 keys per block
#define NWAVES_ 4
#define KPW_    (CHUNK_ / NWAVES_)   // 128 keys per wave
#define NPART_  (NWAVES_ * 2)        // 8 half-wave partials per block
#define PSTRIDE_ (D_ + 2)            // o[128], m, l

__global__ __launch_bounds__(256) void attn_partial_kernel(
    const float* __restrict__ q,
    const float* __restrict__ ck,
    const float* __restrict__ cv,
    const int*   __restrict__ cpos_p,
    float*       __restrict__ part)
{
    const int bh    = blockIdx.x;        // 0..255
    const int split = blockIdx.y;        // 0..7
    const int wave  = threadIdx.x >> 6;  // 0..3
    const int lane  = threadIdx.x & 63;
    const int half  = lane >> 5;         // 0|1 -> which of the 2 keys/iter
    const int li    = lane & 31;         // dim-group owner within half

    const int cpos = cpos_p[0];          // hot loop covers cache rows [0,cpos)

    const float scale = 0.08838834764831845f;  // 1/sqrt(128)

    // lane owns dims 4*li .. 4*li+3 (same dims in both halves)
    const float4 qv = *(const float4*)(q + (size_t)bh * D_ + li * 4);

    const int base  = split * CHUNK_ + wave * KPW_;
    int limit = cpos - base;
    limit = limit < 0 ? 0 : (limit > KPW_ ? KPW_ : limit);

    float  m = -INFINITY;
    float  l = 0.0f;
    float4 o = {0.0f, 0.0f, 0.0f, 0.0f};

    const float* __restrict__ kbase = ck + (size_t)bh * MAXS_ * D_;
    const float* __restrict__ vbase = cv + (size_t)bh * MAXS_ * D_;

    // paired loop: wave covers rows s0 (lanes 0-31) and s0+1 (lanes 32-63);
    // byte address = base + s0*512 + lane*16  -> one contiguous 1KB/load.
    const int npairs = limit >> 1;
    #pragma unroll 2
    for (int i = 0; i < npairs; ++i) {
        const int s0 = base + i * 2;
        const float4 kv = *(const float4*)(kbase + (size_t)s0 * D_ + lane * 4);
        const float4 vv = *(const float4*)(vbase + (size_t)s0 * D_ + lane * 4);

        float dp = kv.x * qv.x + kv.y * qv.y + kv.z * qv.z + kv.w * qv.w;
        dp += __shfl_xor(dp, 16);   // stays within each 32-lane half
        dp += __shfl_xor(dp, 8);
        dp += __shfl_xor(dp, 4);
        dp += __shfl_xor(dp, 2);
        dp += __shfl_xor(dp, 1);

        const float sc   = dp * scale;
        const float mn   = fmaxf(m, sc);
        const float corr = __expf(m - mn);   // first iter: exp(-inf)=0
        const float p    = __expf(sc - mn);
        l   = l   * corr + p;
        o.x = o.x * corr + p * vv.x;
        o.y = o.y * corr + p * vv.y;
        o.z = o.z * corr + p * vv.z;
        o.w = o.w * corr + p * vv.w;
        m = mn;
    }

    // odd tail: one remaining key, processed by half 0 only
    if ((limit & 1) && half == 0) {
        const int s = base + limit - 1;
        const float4 kv = *(const float4*)(kbase + (size_t)s * D_ + li * 4);
        const float4 vv = *(const float4*)(vbase + (size_t)s * D_ + li * 4);
        float dp = kv.x * qv.x + kv.y * qv.y + kv.z * qv.z + kv.w * qv.w;
        dp += __shfl_xor(dp, 16);
        dp += __shfl_xor(dp, 8);
        dp += __shfl_xor(dp, 4);
        dp += __shfl_xor(dp, 2);
        dp += __shfl_xor(dp, 1);
        const float sc   = dp * scale;
        const float mn   = fmaxf(m, sc);
        const float corr = __expf(m - mn);
        const float p    = __expf(sc - mn);
        l   = l   * corr + p;
        o.x = o.x * corr + p * vv.x;
        o.y = o.y * corr + p * vv.y;
        o.z = o.z * corr + p * vv.z;
        o.w = o.w * corr + p * vv.w;
        m = mn;
    }

    // combine the 8 half-wave partials via LDS -> one partial per block
    __shared__ float s_o[NPART_][D_];
    __shared__ float s_m[NPART_];
    __shared__ float s_l[NPART_];
    const int pi = wave * 2 + half;
    *(float4*)&s_o[pi][li * 4] = o;
    if (li == 0) { s_m[pi] = m; s_l[pi] = l; }
    __syncthreads();

    if (wave == 0) {
        float M = -INFINITY;
        #pragma unroll
        for (int p = 0; p < NPART_; ++p) M = fmaxf(M, s_m[p]);

        float* pp = part + ((size_t)bh * NSPLIT_ + split) * PSTRIDE_;
        const int d0 = lane * 2;
        if (M == -INFINITY) {
            // whole block past cpos (cpos small) -- empty partial
            pp[d0]     = 0.0f;
            pp[d0 + 1] = 0.0f;
            if (lane == 0) { pp[D_] = -INFINITY; pp[D_ + 1] = 0.0f; }
        } else {
            float L = 0.0f, a0 = 0.0f, a1 = 0.0f;
            #pragma unroll
            for (int p = 0; p < NPART_; ++p) {
                const float mp = s_m[p];
                const float w  = (mp == -INFINITY) ? 0.0f : __expf(mp - M);
                L  += w * s_l[p];
                a0 += w * s_o[p][d0];
                a1 += w * s_o[p][d0 + 1];
            }
            pp[d0]     = a0;
            pp[d0 + 1] = a1;
            if (lane == 0) { pp[D_] = M; pp[D_ + 1] = L; }
        }
    }
}

// one wave per bh: merges the 8 split partials plus the new key/value
// (which logically replaces cache row cpos) as a 9th partial (m=sc, l=1).
__global__ __launch_bounds__(64) void attn_combine_kernel(
    const float* __restrict__ q,
    const float* __restrict__ knew,
    const float* __restrict__ vnew,
    const float* __restrict__ part,
    float*       __restrict__ out)
{
    const int bh   = blockIdx.x;   // 0..255
    const int lane = threadIdx.x;  // 0..63
    const float scale = 0.08838834764831845f;

    // score of the new key
    const float2 qv = *(const float2*)(q    + (size_t)bh * D_ + lane * 2);
    const float2 kn = *(const float2*)(knew + (size_t)bh * D_ + lane * 2);
    float dp = qv.x * kn.x + qv.y * kn.y;
    #pragma unroll
    for (int off = 32; off > 0; off >>= 1) dp += __shfl_xor(dp, off);
    const float sc = dp * scale;

    const float* pb = part + (size_t)bh * NSPLIT_ * PSTRIDE_;

    float M = sc;
    #pragma unroll
    for (int p = 0; p < NSPLIT_; ++p) M = fmaxf(M, pb[p * PSTRIDE_ + D_]);

    const int d0 = lane * 2;
    const float2 vn = *(const float2*)(vnew + (size_t)bh * D_ + d0);
    const float wn = __expf(sc - M);
    float L  = wn;            // new-key partial has l = 1
    float a0 = wn * vn.x;
    float a1 = wn * vn.y;
    #pragma unroll
    for (int p = 0; p < NSPLIT_; ++p) {
        const float mp = pb[p * PSTRIDE_ + D_];
        const float w  = (mp == -INFINITY) ? 0.0f : __expf(mp - M);
        L  += w * pb[p * PSTRIDE_ + D_ + 1];
        a0 += w * pb[p * PSTRIDE_ + d0];
        a1 += w * pb[p * PSTRIDE_ + d0 + 1];
    }
    out[(size_t)bh * D_ + d0]     = a0 / L;
    out[(size_t)bh * D_ + d0 + 1] = a1 / L;
}

extern "C" void kernel_launch(void* const* d_in, const int* in_sizes, int n_in,
                              void* d_out, int out_size, void* d_ws, size_t ws_size,
                              hipStream_t stream) {
    const float* q    = (const float*)d_in[0];
    const float* knew = (const float*)d_in[1];
    const float* vnew = (const float*)d_in[2];
    const float* ck   = (const float*)d_in[3];
    const float* cv   = (const float*)d_in[4];
    const int*   cpos = (const int*)d_in[5];
    float* out  = (float*)d_out;
    float* part = (float*)d_ws;   // needs 256*8*130*4 = 1,064,960 B

    dim3 grid1(BH_, NSPLIT_);
    attn_partial_kernel<<<grid1, 256, 0, stream>>>(q, ck, cv, cpos, part);
    attn_combine_kernel<<<BH_, 64, 0, stream>>>(q, knew, vnew, part, out);
}

// Round 4
// 179.388 us; speedup vs baseline: 1.3155x; 1.0751x over previous
//
#include <hip/hip_runtime.h>
#include <math.h>

// Cached SDPA decode: B=8 H=32 Q=1 D=128, MAX_SEQ=4096, fp32 in/out.
// Flash-decode split-K. Kernel1: per-(bh,split) online-softmax partials over
// cache rows [0, cpos); new key/value merged as an extra partial in kernel2.
// Two keys per wave-iteration (lanes 0-31 = key s0, lanes 32-63 = key s0+1),
// float4/lane = 16B/lane fully-coalesced 1KB/wave-load.
// R2: explicit 2-stage software pipeline (4 wave-loads in flight ahead of
// use), nontemporal K/V loads, scale folded into q.
// R3: nontemporal loads go through a native ext_vector_type(4) float (the
// builtin rejects HIP_vector_type<float,4>*).

#define BH_     256                  // B*H
#define D_      128
#define MAXS_   4096
#define NSPLIT_ 8
#define CHUNK_  (MAXS_ / NSPLIT_)    // 512 keys per block
#define NWAVES_ 4
#define KPW_    (CHUNK_ / NWAVES_)   // 128 keys per wave
#define NPART_  (NWAVES_ * 2)        // 8 half-wave partials per block
#define PSTRIDE_ (D_ + 2)            // o[128], m, l

typedef float f4n __attribute__((ext_vector_type(4)));

static __device__ __forceinline__ f4n ntld4(const float* p) {
    return __builtin_nontemporal_load((const f4n*)p);
}

__global__ __launch_bounds__(256) void attn_partial_kernel(
    const float* __restrict__ q,
    const float* __restrict__ ck,
    const float* __restrict__ cv,
    const int*   __restrict__ cpos_p,
    float*       __restrict__ part)
{
    const int bh    = blockIdx.x;        // 0..255
    const int split = blockIdx.y;        // 0..7
    const int wave  = threadIdx.x >> 6;  // 0..3
    const int lane  = threadIdx.x & 63;
    const int half  = lane >> 5;         // which of the 2 keys/iter
    const int li    = lane & 31;         // dim-group owner within half

    const int cpos = cpos_p[0];          // hot loop covers cache rows [0,cpos)

    const float scale = 0.08838834764831845f;  // 1/sqrt(128)

    // lane owns dims 4*li .. 4*li+3 (same dims in both halves); scale folded in
    f4n qv = *(const f4n*)(q + (size_t)bh * D_ + li * 4);
    qv *= scale;

    const int base  = split * CHUNK_ + wave * KPW_;
    int limit = cpos - base;
    limit = limit < 0 ? 0 : (limit > KPW_ ? KPW_ : limit);

    float m = -INFINITY;
    float l = 0.0f;
    f4n   o = {0.0f, 0.0f, 0.0f, 0.0f};

    const float* __restrict__ kbase = ck + (size_t)bh * MAXS_ * D_;
    const float* __restrict__ vbase = cv + (size_t)bh * MAXS_ * D_;

#define UPDATE(KV, VV)                                                   \
    do {                                                                 \
        float dp = (KV).x * qv.x + (KV).y * qv.y                         \
                 + (KV).z * qv.z + (KV).w * qv.w;                        \
        dp += __shfl_xor(dp, 16);                                        \
        dp += __shfl_xor(dp, 8);                                         \
        dp += __shfl_xor(dp, 4);                                         \
        dp += __shfl_xor(dp, 2);                                         \
        dp += __shfl_xor(dp, 1);                                         \
        const float mn   = fmaxf(m, dp);                                 \
        const float corr = __expf(m - mn);                               \
        const float p    = __expf(dp - mn);                              \
        l   = l   * corr + p;                                            \
        o.x = o.x * corr + p * (VV).x;                                   \
        o.y = o.y * corr + p * (VV).y;                                   \
        o.z = o.z * corr + p * (VV).z;                                   \
        o.w = o.w * corr + p * (VV).w;                                   \
        m = mn;                                                          \
    } while (0)

    if (limit == KPW_) {
        // fast path: full 128-key tile, 2-stage pipelined (2 pairs ahead)
        const float* kp = kbase + (size_t)base * D_ + lane * 4;
        const float* vp = vbase + (size_t)base * D_ + lane * 4;
        f4n ka = ntld4(kp),        va = ntld4(vp);
        f4n kb = ntld4(kp + 256),  vb = ntld4(vp + 256);
        kp += 512; vp += 512;
        for (int i = 0; i < 31; ++i) {
            const f4n kc = ntld4(kp),       vc = ntld4(vp);
            const f4n kd = ntld4(kp + 256), vd = ntld4(vp + 256);
            kp += 512; vp += 512;
            UPDATE(ka, va);
            UPDATE(kb, vb);
            ka = kc; va = vc; kb = kd; vb = vd;
        }
        UPDATE(ka, va);
        UPDATE(kb, vb);
    } else {
        // generic path: paired loop + odd tail (half 0 only)
        const int npairs = limit >> 1;
        for (int i = 0; i < npairs; ++i) {
            const int s0 = base + i * 2;
            const f4n kv = ntld4(kbase + (size_t)s0 * D_ + lane * 4);
            const f4n vv = ntld4(vbase + (size_t)s0 * D_ + lane * 4);
            UPDATE(kv, vv);
        }
        if ((limit & 1) && half == 0) {
            const int s = base + limit - 1;
            const f4n kv = ntld4(kbase + (size_t)s * D_ + li * 4);
            const f4n vv = ntld4(vbase + (size_t)s * D_ + li * 4);
            UPDATE(kv, vv);
        }
    }
#undef UPDATE

    // combine the 8 half-wave partials via LDS -> one partial per block
    __shared__ float s_o[NPART_][D_];
    __shared__ float s_m[NPART_];
    __shared__ float s_l[NPART_];
    const int pi = wave * 2 + half;
    *(f4n*)&s_o[pi][li * 4] = o;
    if (li == 0) { s_m[pi] = m; s_l[pi] = l; }
    __syncthreads();

    if (wave == 0) {
        float M = -INFINITY;
        #pragma unroll
        for (int p = 0; p < NPART_; ++p) M = fmaxf(M, s_m[p]);

        float* pp = part + ((size_t)bh * NSPLIT_ + split) * PSTRIDE_;
        const int d0 = lane * 2;
        if (M == -INFINITY) {
            pp[d0]     = 0.0f;
            pp[d0 + 1] = 0.0f;
            if (lane == 0) { pp[D_] = -INFINITY; pp[D_ + 1] = 0.0f; }
        } else {
            float L = 0.0f, a0 = 0.0f, a1 = 0.0f;
            #pragma unroll
            for (int p = 0; p < NPART_; ++p) {
                const float mp = s_m[p];
                const float w  = (mp == -INFINITY) ? 0.0f : __expf(mp - M);
                L  += w * s_l[p];
                a0 += w * s_o[p][d0];
                a1 += w * s_o[p][d0 + 1];
            }
            pp[d0]     = a0;
            pp[d0 + 1] = a1;
            if (lane == 0) { pp[D_] = M; pp[D_ + 1] = L; }
        }
    }
}

// one wave per bh: merges the 8 split partials plus the new key/value
// (which logically replaces cache row cpos) as a 9th partial (m=sc, l=1).
__global__ __launch_bounds__(64) void attn_combine_kernel(
    const float* __restrict__ q,
    const float* __restrict__ knew,
    const float* __restrict__ vnew,
    const float* __restrict__ part,
    float*       __restrict__ out)
{
    const int bh   = blockIdx.x;   // 0..255
    const int lane = threadIdx.x;  // 0..63
    const float scale = 0.08838834764831845f;

    const float2 qv = *(const float2*)(q    + (size_t)bh * D_ + lane * 2);
    const float2 kn = *(const float2*)(knew + (size_t)bh * D_ + lane * 2);
    float dp = qv.x * kn.x + qv.y * kn.y;
    #pragma unroll
    for (int off = 32; off > 0; off >>= 1) dp += __shfl_xor(dp, off);
    const float sc = dp * scale;

    const float* pb = part + (size_t)bh * NSPLIT_ * PSTRIDE_;

    float M = sc;
    #pragma unroll
    for (int p = 0; p < NSPLIT_; ++p) M = fmaxf(M, pb[p * PSTRIDE_ + D_]);

    const int d0 = lane * 2;
    const float2 vn = *(const float2*)(vnew + (size_t)bh * D_ + d0);
    const float wn = __expf(sc - M);
    float L  = wn;            // new-key partial has l = 1
    float a0 = wn * vn.x;
    float a1 = wn * vn.y;
    #pragma unroll
    for (int p = 0; p < NSPLIT_; ++p) {
        const float mp = pb[p * PSTRIDE_ + D_];
        const float w  = (mp == -INFINITY) ? 0.0f : __expf(mp - M);
        L  += w * pb[p * PSTRIDE_ + D_ + 1];
        a0 += w * pb[p * PSTRIDE_ + d0];
        a1 += w * pb[p * PSTRIDE_ + d0 + 1];
    }
    out[(size_t)bh * D_ + d0]     = a0 / L;
    out[(size_t)bh * D_ + d0 + 1] = a1 / L;
}

extern "C" void kernel_launch(void* const* d_in, const int* in_sizes, int n_in,
                              void* d_out, int out_size, void* d_ws, size_t ws_size,
                              hipStream_t stream) {
    const float* q    = (const float*)d_in[0];
    const float* knew = (const float*)d_in[1];
    const float* vnew = (const float*)d_in[2];
    const float* ck   = (const float*)d_in[3];
    const float* cv   = (const float*)d_in[4];
    const int*   cpos = (const int*)d_in[5];
    float* out  = (float*)d_out;
    float* part = (float*)d_ws;   // needs 256*8*130*4 = 1,064,960 B

    dim3 grid1(BH_, NSPLIT_);
    attn_partial_kernel<<<grid1, 256, 0, stream>>>(q, ck, cv, cpos, part);
    attn_combine_kernel<<<BH_, 64, 0, stream>>>(q, knew, vnew, part, out);
}